// Round 1
// baseline (284.355 us; speedup 1.0000x reference)
//
#include <hip/hip_runtime.h>
#include <hip/hip_bf16.h>

#define N_    2048
#define FIN   256
#define FOUT  128
#define ALPHA 0.01f
#define NEGINF -1000000000000.0f

typedef short bf16x8 __attribute__((ext_vector_type(8)));
typedef float f32x4  __attribute__((ext_vector_type(4)));

static __device__ __forceinline__ unsigned short f2bf(float x) {
    __hip_bfloat16 h = __float2bfloat16(x);
    return *reinterpret_cast<unsigned short*>(&h);
}

// Kernel 1: h = inp @ W (fp32), emit s1 = h.a1, s2 = h.a2 (fp32) and hT (bf16, [b][f][n])
__global__ __launch_bounds__(256) void k_lin(
    const float* __restrict__ inp, const float* __restrict__ W,
    const float* __restrict__ av, __hip_bfloat16* __restrict__ hT,
    float* __restrict__ s1, float* __restrict__ s2)
{
    __shared__ float in_lds[32 * FIN];   // 32 KB
    int g = blockIdx.x;                  // 512 blocks
    int b = g & 7;                       // XCD-affine: batch -> XCD
    int tile = g >> 3;                   // 0..63
    int i0 = tile << 5;                  // 32 rows per block
    int t = threadIdx.x;

    const float4* src = reinterpret_cast<const float4*>(inp + ((size_t)(b * N_ + i0)) * FIN);
    float4* dst = reinterpret_cast<float4*>(in_lds);
#pragma unroll
    for (int c = 0; c < 8; ++c) dst[t + 256 * c] = src[t + 256 * c];
    __syncthreads();

    int fq = t & 31;    // feature quad: f = fq*4 .. fq*4+3
    int rg = t >> 5;    // row group: rows rg*4 .. rg*4+3
    float acc[4][4];
#pragma unroll
    for (int r = 0; r < 4; ++r)
#pragma unroll
        for (int j = 0; j < 4; ++j) acc[r][j] = 0.f;

    const float4* W4 = reinterpret_cast<const float4*>(W);
    for (int k = 0; k < FIN; k += 4) {
        float4 inr[4];
#pragma unroll
        for (int r = 0; r < 4; ++r)
            inr[r] = *reinterpret_cast<const float4*>(&in_lds[(rg * 4 + r) * FIN + k]);
#pragma unroll
        for (int kk = 0; kk < 4; ++kk) {
            float4 w4 = W4[(k + kk) * 32 + fq];
#pragma unroll
            for (int r = 0; r < 4; ++r) {
                float iv = (&inr[r].x)[kk];
                acc[r][0] = fmaf(iv, w4.x, acc[r][0]);
                acc[r][1] = fmaf(iv, w4.y, acc[r][1]);
                acc[r][2] = fmaf(iv, w4.z, acc[r][2]);
                acc[r][3] = fmaf(iv, w4.w, acc[r][3]);
            }
        }
    }

    // s1/s2: reduce h . a1 / a2 across the 32 fq-lanes (per 32-lane half-wave)
    float a1v[4], a2v[4];
#pragma unroll
    for (int j = 0; j < 4; ++j) {
        a1v[j] = av[fq * 4 + j];
        a2v[j] = av[FOUT + fq * 4 + j];
    }
#pragma unroll
    for (int r = 0; r < 4; ++r) {
        float p1 = acc[r][0] * a1v[0] + acc[r][1] * a1v[1] + acc[r][2] * a1v[2] + acc[r][3] * a1v[3];
        float p2 = acc[r][0] * a2v[0] + acc[r][1] * a2v[1] + acc[r][2] * a2v[2] + acc[r][3] * a2v[3];
#pragma unroll
        for (int off = 1; off < 32; off <<= 1) {
            p1 += __shfl_xor(p1, off);
            p2 += __shfl_xor(p2, off);
        }
        if (fq == 0) {
            int row = i0 + rg * 4 + r;
            s1[b * N_ + row] = p1;
            s2[b * N_ + row] = p2;
        }
    }

    // hT[b][f][n] bf16, n contiguous (4 rows per thread -> ushort4 store)
#pragma unroll
    for (int j = 0; j < 4; ++j) {
        ushort4 pk;
        pk.x = f2bf(acc[0][j]);
        pk.y = f2bf(acc[1][j]);
        pk.z = f2bf(acc[2][j]);
        pk.w = f2bf(acc[3][j]);
        *reinterpret_cast<ushort4*>(
            &hT[((size_t)(b * FOUT + fq * 4 + j)) * N_ + i0 + rg * 4]) = pk;
    }
}

// Kernel 2: fused masked-softmax attention + PV (bf16 MFMA) + ReLU.
// Block = 16 i-rows, 4 waves; wave w handles j in [w*512, w*512+512).
__global__ __launch_bounds__(256, 4) void k_attn(
    const int* __restrict__ adj, const __hip_bfloat16* __restrict__ hT,
    const float* __restrict__ s1g, const float* __restrict__ s2g,
    float* __restrict__ out)
{
    __shared__ float m_s[4][16];
    __shared__ float l_s[4][16];
    __shared__ float L_s[16];
    __shared__ float accb[4][16][132];   // padded: +4 breaks 4-way bank alias

    int g = blockIdx.x;                  // 1024 blocks
    int b = g & 7;                       // XCD-affine: batch -> XCD (hT[b] stays L2-local)
    int tile = g >> 3;                   // 0..127
    int i0 = tile << 4;                  // 16 rows
    int t = threadIdx.x;
    int w = t >> 6;
    int l = t & 63;
    int r = l & 15;                      // A-operand row (score row for this lane)
    int lg = l >> 4;                     // k-group
    int jc = w * 512;

    const float s1r = s1g[b * N_ + i0 + r];
    size_t adj_off = ((size_t)(b * N_ + i0 + r)) * N_ + jc + lg * 8;
    const int4*   adjp = reinterpret_cast<const int4*>(adj + adj_off);
    const float4* s2p  = reinterpret_cast<const float4*>(s2g + b * N_ + jc + lg * 8);
    const bf16x8* hv   = reinterpret_cast<const bf16x8*>(hT);
    size_t h0 = (((size_t)(b * FOUT + r)) * N_ + jc + lg * 8) >> 3;
    const size_t FRAG_STRIDE = (size_t)16 * N_ / 8;   // 16 f-rows ahead

    float m_run = -3.0e38f;
    float l_run = 0.0f;
    f32x4 acc[8];
#pragma unroll
    for (int q = 0; q < 8; ++q) acc[q] = (f32x4){0.f, 0.f, 0.f, 0.f};

    for (int step = 0; step < 16; ++step) {
        int4 aj0 = adjp[step * 8];
        int4 aj1 = adjp[step * 8 + 1];
        float4 s2a = s2p[step * 8];
        float4 s2b = s2p[step * 8 + 1];

        float ev[8];
        ev[0] = s1r + s2a.x; ev[1] = s1r + s2a.y; ev[2] = s1r + s2a.z; ev[3] = s1r + s2a.w;
        ev[4] = s1r + s2b.x; ev[5] = s1r + s2b.y; ev[6] = s1r + s2b.z; ev[7] = s1r + s2b.w;
        int aji[8] = {aj0.x, aj0.y, aj0.z, aj0.w, aj1.x, aj1.y, aj1.z, aj1.w};
#pragma unroll
        for (int e = 0; e < 8; ++e) {
            float v = ev[e];
            v = fmaxf(v, ALPHA * v);              // leaky relu
            ev[e] = (aji[e] > 0) ? v : NEGINF;    // mask
        }
        // tile max for this row (4 lanes per row: xor 16, 32)
        float mt = fmaxf(fmaxf(fmaxf(ev[0], ev[1]), fmaxf(ev[2], ev[3])),
                         fmaxf(fmaxf(ev[4], ev[5]), fmaxf(ev[6], ev[7])));
        mt = fmaxf(mt, __shfl_xor(mt, 16));
        mt = fmaxf(mt, __shfl_xor(mt, 32));

        if (__any(mt > m_run)) {
            float sc = (mt > m_run) ? __expf(m_run - mt) : 1.0f;   // per score-row factor
            m_run = fmaxf(m_run, mt);
            l_run *= sc;
            // acc rows are lg*4+rr, not r: pull those rows' factors from lanes 0..15
            float sr0 = __shfl(sc, lg * 4 + 0);
            float sr1 = __shfl(sc, lg * 4 + 1);
            float sr2 = __shfl(sc, lg * 4 + 2);
            float sr3 = __shfl(sc, lg * 4 + 3);
            f32x4 srv = (f32x4){sr0, sr1, sr2, sr3};
#pragma unroll
            for (int q = 0; q < 8; ++q) acc[q] *= srv;
        }

        bf16x8 af;
        float ps = 0.f;
#pragma unroll
        for (int e = 0; e < 8; ++e) {
            float p = __expf(ev[e] - m_run);
            ps += p;
            af[e] = (short)f2bf(p);
        }
        l_run += ps;

#pragma unroll
        for (int q = 0; q < 8; ++q) {
            bf16x8 bfr = hv[h0 + (size_t)q * FRAG_STRIDE + step * 4];
            acc[q] = __builtin_amdgcn_mfma_f32_16x16x32_bf16(af, bfr, acc[q], 0, 0, 0);
        }
    }

    // ---- merge the 4 j-chunks ----
    l_run += __shfl_xor(l_run, 16);
    l_run += __shfl_xor(l_run, 32);
    if (l < 16) { m_s[w][l] = m_run; l_s[w][l] = l_run; }
    __syncthreads();

    float mysc[4];
#pragma unroll
    for (int rr = 0; rr < 4; ++rr) {
        int ir = lg * 4 + rr;
        float M = fmaxf(fmaxf(m_s[0][ir], m_s[1][ir]), fmaxf(m_s[2][ir], m_s[3][ir]));
        float Ls = l_s[0][ir] * __expf(m_s[0][ir] - M)
                 + l_s[1][ir] * __expf(m_s[1][ir] - M)
                 + l_s[2][ir] * __expf(m_s[2][ir] - M)
                 + l_s[3][ir] * __expf(m_s[3][ir] - M);
        mysc[rr] = __expf(m_s[w][ir] - M);
        if (w == 0 && r == 0) L_s[ir] = Ls;   // lanes 0,16,32,48 cover all 16 rows
    }
#pragma unroll
    for (int q = 0; q < 8; ++q)
#pragma unroll
        for (int rr = 0; rr < 4; ++rr)
            accb[w][lg * 4 + rr][q * 16 + r] = acc[q][rr] * mysc[rr];
    __syncthreads();

    int f = t & 127;
    int rh = t >> 7;
#pragma unroll
    for (int rr = 0; rr < 8; ++rr) {
        int row = rh * 8 + rr;
        float v = accb[0][row][f] + accb[1][row][f] + accb[2][row][f] + accb[3][row][f];
        v = v / L_s[row];
        out[((size_t)(b * N_ + i0 + row)) * FOUT + f] = fmaxf(v, 0.f);
    }
}

extern "C" void kernel_launch(void* const* d_in, const int* in_sizes, int n_in,
                              void* d_out, int out_size, void* d_ws, size_t ws_size,
                              hipStream_t stream) {
    (void)in_sizes; (void)n_in; (void)out_size; (void)ws_size;
    const float* inp = (const float*)d_in[0];
    const int*   adj = (const int*)d_in[1];
    const float* W   = (const float*)d_in[2];
    const float* a   = (const float*)d_in[3];
    float* out = (float*)d_out;

    char* ws = (char*)d_ws;
    __hip_bfloat16* hT = (__hip_bfloat16*)ws;                      // 8*128*2048*2 B = 4 MB
    float* s1 = (float*)(ws + (size_t)8 * FOUT * N_ * 2);          // 64 KB
    float* s2 = s1 + 8 * N_;                                       // 64 KB

    k_lin<<<512, 256, 0, stream>>>(inp, W, a, hT, s1, s2);
    k_attn<<<1024, 256, 0, stream>>>(adj, hT, s1, s2, out);
}